// Round 2
// baseline (330.303 us; speedup 1.0000x reference)
//
#include <hip/hip_runtime.h>

#define C_IN   2048
#define HWSZ   1024
#define NBATCH 16
#define C_OUT  512
#define BM 128
#define BN 128
#define BK 32
#define NKSTEP (C_IN/BK)   // 64

typedef __attribute__((ext_vector_type(4))) float f32x4;
typedef __attribute__((ext_vector_type(8))) short bf16x8;

__device__ __forceinline__ unsigned short f2bf(float x){
  unsigned int u = __float_as_uint(x);
  u += 0x7fffu + ((u >> 16) & 1u);          // RNE
  return (unsigned short)(u >> 16);
}
__device__ __forceinline__ float bf2f(unsigned short h){
  return __uint_as_float(((unsigned int)h) << 16);
}

// Gather center tap W[o][c][4][0] and split fp32 -> bf16 hi/lo pair.
__global__ void prep_w_kernel(const float* __restrict__ W,
                              unsigned short* __restrict__ Wh,
                              unsigned short* __restrict__ Wl){
  int i = blockIdx.x * 256 + threadIdx.x;   // 0 .. C_OUT*C_IN-1
  float x = W[(size_t)i * 9 + 4];
  unsigned short h = f2bf(x);
  Wh[i] = h;
  Wl[i] = f2bf(x - bf2f(h));
}

union FragU { bf16x8 v; uint2 u[2]; };

// C[o,p] = sum_c W[o,c]*F[c,p] via 3-pass bf16-split MFMA.
// LDS tiles [rows][BK] bf16 with 8-byte-group XOR swizzle: elem(r,c) ->
// r*BK + ((c>>2) ^ ((r>>2)&7))*4 + (c&3). Frag reads = 2x ds_read_b64, ~2-way.
__global__ __launch_bounds__(256, 2) void gemm_kernel(
    const float* __restrict__ fea,
    const unsigned short* __restrict__ Wh,
    const unsigned short* __restrict__ Wl,
    const float* __restrict__ bias,
    float* __restrict__ out)
{
  __shared__ unsigned short Ah[BM*BK], Al[BM*BK], Bh[BN*BK], Bl[BN*BK];
  __shared__ float bias_s[BM];

  const int t   = threadIdx.x;
  const int l   = t & 63;
  const int wid = t >> 6;
  const int bx  = blockIdx.x;
  const int mt  = bx & 3;          // o-tile (4) — fastest: 4 blocks share F panel (L2)
  const int pt  = (bx >> 2) & 7;   // p-tile (8)
  const int nb  = bx >> 5;         // batch (16)

  if (t < BM) bias_s[t] = bias[mt*BM + t];

  const unsigned short* whg = Wh + (size_t)mt*BM*C_IN;
  const unsigned short* wlg = Wl + (size_t)mt*BM*C_IN;
  const float* fg = fea + (size_t)nb*C_IN*HWSZ + (size_t)pt*BN;

  const int wr0 = t >> 2;          // W staging row, round 0 (0..63)
  const int wh4 = t & 3;           // 16B chunk within W row
  const int cb  = t >> 5;          // F c sub-block (0..7)
  const int pb  = t & 31;          // F p sub-block (0..31)

  f32x4 acc[4][4];
  #pragma unroll
  for (int i=0;i<4;i++)
    #pragma unroll
    for (int j=0;j<4;j++) acc[i][j] = (f32x4)0.0f;

  uint4 wvh[2], wvl[2];
  f32x4 fv[4];

  // prologue: global loads for ks=0
  {
    #pragma unroll
    for (int i=0;i<2;i++){
      const size_t ro = (size_t)(wr0 + i*64) * C_IN + wh4*8;
      wvh[i] = *(const uint4*)(whg + ro);
      wvl[i] = *(const uint4*)(wlg + ro);
    }
    #pragma unroll
    for (int i=0;i<4;i++)
      fv[i] = *(const f32x4*)(fg + (size_t)(cb*4 + i)*HWSZ + pb*4);
  }

  const int fr    = l & 15;
  const int o2    = l >> 4;
  const int mrow0 = (wid >> 1) * 64;
  const int ncol0 = (wid & 1) * 64;

  for (int ks = 0; ks < NKSTEP; ks++){
    __syncthreads();                       // prev tile's reads done
    // ---- stage W (already bf16) with swizzle
    #pragma unroll
    for (int i=0;i<2;i++){
      const int r    = wr0 + i*64;
      const int key  = (r >> 2) & 7;
      const int base = r * BK;
      uint2 v0, v1;
      v0.x = wvh[i].x; v0.y = wvh[i].y;
      v1.x = wvh[i].z; v1.y = wvh[i].w;
      *(uint2*)&Ah[base + (((wh4*2)    ) ^ key)*4] = v0;
      *(uint2*)&Ah[base + (((wh4*2) + 1) ^ key)*4] = v1;
      v0.x = wvl[i].x; v0.y = wvl[i].y;
      v1.x = wvl[i].z; v1.y = wvl[i].w;
      *(uint2*)&Al[base + (((wh4*2)    ) ^ key)*4] = v0;
      *(uint2*)&Al[base + (((wh4*2) + 1) ^ key)*4] = v1;
    }
    // ---- stage F: fp32 -> bf16 hi/lo, 4x4 in-register transpose
    {
      unsigned short hb[4][4], lb[4][4];
      #pragma unroll
      for (int i=0;i<4;i++)
        #pragma unroll
        for (int j=0;j<4;j++){
          float x = fv[i][j];
          unsigned short h = f2bf(x);
          hb[i][j] = h;
          lb[i][j] = f2bf(x - bf2f(h));
        }
      const int g = (cb ^ (pb & 7)) * 4;   // key(p) = (p>>2)&7 = pb&7
      #pragma unroll
      for (int j=0;j<4;j++){
        const int p    = pb*4 + j;
        const int base = p*BK + g;
        uint2 vh, vl;
        vh.x = (unsigned)hb[0][j] | ((unsigned)hb[1][j] << 16);
        vh.y = (unsigned)hb[2][j] | ((unsigned)hb[3][j] << 16);
        vl.x = (unsigned)lb[0][j] | ((unsigned)lb[1][j] << 16);
        vl.y = (unsigned)lb[2][j] | ((unsigned)lb[3][j] << 16);
        *(uint2*)&Bh[base] = vh;
        *(uint2*)&Bl[base] = vl;
      }
    }
    __syncthreads();

    // ---- prefetch next K-step (overlaps MFMA below)
    if (ks + 1 < NKSTEP){
      const int c0 = (ks + 1) * BK;
      #pragma unroll
      for (int i=0;i<2;i++){
        const size_t ro = (size_t)(wr0 + i*64) * C_IN + c0 + wh4*8;
        wvh[i] = *(const uint4*)(whg + ro);
        wvl[i] = *(const uint4*)(wlg + ro);
      }
      #pragma unroll
      for (int i=0;i<4;i++)
        fv[i] = *(const f32x4*)(fg + (size_t)(c0 + cb*4 + i)*HWSZ + pb*4);
    }

    // ---- fragment loads (2x b64 each, un-swizzled on the fly)
    FragU ahf[4], alf[4], bhf[4], blf[4];
    #pragma unroll
    for (int mf=0; mf<4; mf++){
      const int r   = mrow0 + mf*16 + fr;
      const int key = (r >> 2) & 7;
      const int b0  = r*BK + ((2*o2    ) ^ key)*4;
      const int b1  = r*BK + ((2*o2 + 1) ^ key)*4;
      ahf[mf].u[0] = *(const uint2*)&Ah[b0];
      ahf[mf].u[1] = *(const uint2*)&Ah[b1];
      alf[mf].u[0] = *(const uint2*)&Al[b0];
      alf[mf].u[1] = *(const uint2*)&Al[b1];
    }
    #pragma unroll
    for (int nf=0; nf<4; nf++){
      const int p   = ncol0 + nf*16 + fr;
      const int key = (p >> 2) & 7;
      const int b0  = p*BK + ((2*o2    ) ^ key)*4;
      const int b1  = p*BK + ((2*o2 + 1) ^ key)*4;
      bhf[nf].u[0] = *(const uint2*)&Bh[b0];
      bhf[nf].u[1] = *(const uint2*)&Bh[b1];
      blf[nf].u[0] = *(const uint2*)&Bl[b0];
      blf[nf].u[1] = *(const uint2*)&Bl[b1];
    }

    // ---- 3-pass split MFMA: acc += Ah*Bh + Ah*Bl + Al*Bh (lo*lo dropped)
    #pragma unroll
    for (int mf=0; mf<4; mf++)
      #pragma unroll
      for (int nf=0; nf<4; nf++){
        acc[mf][nf] = __builtin_amdgcn_mfma_f32_16x16x32_bf16(ahf[mf].v, bhf[nf].v, acc[mf][nf], 0, 0, 0);
        acc[mf][nf] = __builtin_amdgcn_mfma_f32_16x16x32_bf16(ahf[mf].v, blf[nf].v, acc[mf][nf], 0, 0, 0);
        acc[mf][nf] = __builtin_amdgcn_mfma_f32_16x16x32_bf16(alf[mf].v, bhf[nf].v, acc[mf][nf], 0, 0, 0);
      }
  }

  // ---- epilogue: bias + relu + store (C/D: col=lane&15, row=(lane>>4)*4+reg)
  float* ob = out + ((size_t)nb*C_OUT + mt*BM) * HWSZ + (size_t)pt*BN;
  #pragma unroll
  for (int mf=0; mf<4; mf++){
    #pragma unroll
    for (int nf=0; nf<4; nf++){
      const int p = ncol0 + nf*16 + fr;
      #pragma unroll
      for (int rr=0; rr<4; rr++){
        const int o = mrow0 + mf*16 + o2*4 + rr;
        float x = acc[mf][nf][rr] + bias_s[o];
        x = fmaxf(x, 0.0f);
        ob[(size_t)o*HWSZ + p] = x;
      }
    }
  }
}

extern "C" void kernel_launch(void* const* d_in, const int* in_sizes, int n_in,
                              void* d_out, int out_size, void* d_ws, size_t ws_size,
                              hipStream_t stream){
  const float* fea = (const float*)d_in[0];
  const float* W   = (const float*)d_in[1];
  const float* b   = (const float*)d_in[2];
  float* out = (float*)d_out;
  unsigned short* Wh = (unsigned short*)d_ws;                 // 2 MB
  unsigned short* Wl = Wh + (size_t)C_OUT*C_IN;               // 2 MB
  prep_w_kernel<<<dim3((C_OUT*C_IN)/256), dim3(256), 0, stream>>>(W, Wh, Wl);
  gemm_kernel<<<dim3(4*8*NBATCH), dim3(256), 0, stream>>>(fea, Wh, Wl, b, out);
}

// Round 3
// 306.827 us; speedup vs baseline: 1.0765x; 1.0765x over previous
//
#include <hip/hip_runtime.h>

#define C_IN   2048
#define HWSZ   1024
#define NBATCH 16
#define C_OUT  512
#define BM 128
#define BN 128
#define BK 64
#define NKSTEP (C_IN/BK)   // 32

typedef __attribute__((ext_vector_type(4))) float f32x4;
typedef __attribute__((ext_vector_type(8))) short bf16x8;

__device__ __forceinline__ unsigned short f2bf(float x){
  unsigned int u = __float_as_uint(x);
  u += 0x7fffu + ((u >> 16) & 1u);          // RNE
  return (unsigned short)(u >> 16);
}

// Gather center tap W[o][c][4][0] -> bf16 (single-pass: absmax round-2 showed
// plain-bf16-level error regardless of hi/lo split, and it passes).
__global__ void prep_w_kernel(const float* __restrict__ W,
                              unsigned short* __restrict__ Wh){
  int i = blockIdx.x * 256 + threadIdx.x;   // 0 .. C_OUT*C_IN-1
  Wh[i] = f2bf(W[(size_t)i * 9 + 4]);
}

union FragU { bf16x8 v; uint4 q; };

// C[o,p] = sum_c W[o,c]*F[c,p], single-pass bf16 MFMA.
// LDS tiles [rows][BK=64] bf16; 8B-group XOR swizzle with EVEN key
// key(r) = (r&7)<<1 so every access is one b128 (16B groups stay adjacent).
// Frag reads: 16 lanes span 8 keys -> 2 lanes/bank-quad = free (m136).
__global__ __launch_bounds__(256, 2) void gemm_kernel(
    const float* __restrict__ fea,
    const unsigned short* __restrict__ Wh,
    const float* __restrict__ bias,
    float* __restrict__ out)
{
  __shared__ unsigned short Ah[BM*BK];   // 16 KB
  __shared__ unsigned short Bh[BN*BK];   // 16 KB
  __shared__ float bias_s[BM];

  const int t   = threadIdx.x;
  const int l   = t & 63;
  const int wid = t >> 6;

  // XCD-aware decode: dispatcher round-robins blockIdx%8 across XCDs.
  // Give each XCD 16 whole (nb,pt) panels; the 4 o-tiles sharing a panel
  // land on the SAME XCD so the 1 MB fea panel is fetched once per chip.
  const int bx  = blockIdx.x;          // 512 blocks
  const int xcd = bx & 7;
  const int s_  = bx >> 3;             // 0..63
  const int mt  = s_ & 3;              // o-tile within panel
  const int pl  = xcd * 16 + (s_ >> 2);// panel 0..127
  const int pt  = pl & 7;
  const int nb  = pl >> 3;

  if (t < BM) bias_s[t] = bias[mt*BM + t];

  const unsigned short* whg = Wh + (size_t)mt*BM*C_IN;
  const float* fg = fea + (size_t)nb*C_IN*HWSZ + (size_t)pt*BN;

  const int wr0 = t >> 2;          // W staging row (0..63), +64 on 2nd pass
  const int wh4 = t & 3;           // 16B chunk within row half
  const int cb  = t >> 5;          // F c sub-block (0..7)
  const int pb  = t & 31;          // F p quad (0..31)

  f32x4 acc[4][4];
  #pragma unroll
  for (int i=0;i<4;i++)
    #pragma unroll
    for (int j=0;j<4;j++) acc[i][j] = (f32x4)0.0f;

  uint4 wv[2][2];    // [row-half i][col-half h]
  f32x4 fv[8];

  // prologue: global loads for ks=0
  #pragma unroll
  for (int i=0;i<2;i++)
    #pragma unroll
    for (int h=0;h<2;h++)
      wv[i][h] = *(const uint4*)(whg + (size_t)(wr0 + i*64)*C_IN + h*32 + wh4*8);
  #pragma unroll
  for (int i=0;i<8;i++)
    fv[i] = *(const f32x4*)(fg + (size_t)(cb*8 + i)*HWSZ + pb*4);

  const int fr    = l & 15;
  const int o2    = l >> 4;
  const int mrow0 = (wid >> 1) * 64;
  const int ncol0 = (wid & 1) * 64;

  for (int ks = 0; ks < NKSTEP; ks++){
    __syncthreads();                       // prev tile's reads done
    // ---- stage W (bf16, b128 writes, swizzled)
    #pragma unroll
    for (int i=0;i<2;i++){
      const int r   = wr0 + i*64;
      const int key = (r & 7) << 1;
      #pragma unroll
      for (int h=0;h<2;h++){
        const int q0 = h*8 + wh4*2;        // k-quad index (0..15)
        *(uint4*)&Ah[r*BK + ((q0 ^ key))*4] = wv[i][h];
      }
    }
    // ---- stage F: fp32 -> bf16, 8x4 in-register transpose, b128 writes
    {
      unsigned short hb[8][4];
      #pragma unroll
      for (int i=0;i<8;i++)
        #pragma unroll
        for (int j=0;j<4;j++) hb[i][j] = f2bf(fv[i][j]);
      #pragma unroll
      for (int j=0;j<4;j++){
        const int p   = pb*4 + j;
        const int key = (p & 7) << 1;
        uint4 v;
        v.x = (unsigned)hb[0][j] | ((unsigned)hb[1][j] << 16);
        v.y = (unsigned)hb[2][j] | ((unsigned)hb[3][j] << 16);
        v.z = (unsigned)hb[4][j] | ((unsigned)hb[5][j] << 16);
        v.w = (unsigned)hb[6][j] | ((unsigned)hb[7][j] << 16);
        *(uint4*)&Bh[p*BK + (((2*cb) ^ key))*4] = v;
      }
    }
    __syncthreads();

    // ---- prefetch next K-step into regs (overlaps MFMA below)
    if (ks + 1 < NKSTEP){
      const int c0 = (ks + 1) * BK;
      #pragma unroll
      for (int i=0;i<2;i++)
        #pragma unroll
        for (int h=0;h<2;h++)
          wv[i][h] = *(const uint4*)(whg + (size_t)(wr0 + i*64)*C_IN + c0 + h*32 + wh4*8);
      #pragma unroll
      for (int i=0;i<8;i++)
        fv[i] = *(const f32x4*)(fg + (size_t)(c0 + cb*8 + i)*HWSZ + pb*4);
    }

    // ---- fragment loads: one ds_read_b128 per frag per k-slice
    FragU af[4][2], bff[4][2];
    #pragma unroll
    for (int mf=0; mf<4; mf++){
      const int r   = mrow0 + mf*16 + fr;
      const int key = (r & 7) << 1;
      #pragma unroll
      for (int s=0; s<2; s++)
        af[mf][s].q = *(const uint4*)&Ah[r*BK + (((s*8 + 2*o2) ^ key))*4];
    }
    #pragma unroll
    for (int nf=0; nf<4; nf++){
      const int p   = ncol0 + nf*16 + fr;
      const int key = (p & 7) << 1;
      #pragma unroll
      for (int s=0; s<2; s++)
        bff[nf][s].q = *(const uint4*)&Bh[p*BK + (((s*8 + 2*o2) ^ key))*4];
    }

    // ---- 32 MFMA per wave per K-step
    #pragma unroll
    for (int mf=0; mf<4; mf++)
      #pragma unroll
      for (int nf=0; nf<4; nf++)
        #pragma unroll
        for (int s=0; s<2; s++)
          acc[mf][nf] = __builtin_amdgcn_mfma_f32_16x16x32_bf16(af[mf][s].v, bff[nf][s].v, acc[mf][nf], 0, 0, 0);
  }

  // ---- epilogue: bias + relu + store (C/D: col=lane&15, row=(lane>>4)*4+reg)
  float* ob = out + ((size_t)nb*C_OUT + mt*BM) * HWSZ + (size_t)pt*BN;
  #pragma unroll
  for (int mf=0; mf<4; mf++){
    #pragma unroll
    for (int nf=0; nf<4; nf++){
      const int p = ncol0 + nf*16 + fr;
      #pragma unroll
      for (int rr=0; rr<4; rr++){
        const int o = mrow0 + mf*16 + o2*4 + rr;
        float x = acc[mf][nf][rr] + bias_s[o];
        x = fmaxf(x, 0.0f);
        ob[(size_t)o*HWSZ + p] = x;
      }
    }
  }
}

extern "C" void kernel_launch(void* const* d_in, const int* in_sizes, int n_in,
                              void* d_out, int out_size, void* d_ws, size_t ws_size,
                              hipStream_t stream){
  const float* fea = (const float*)d_in[0];
  const float* W   = (const float*)d_in[1];
  const float* b   = (const float*)d_in[2];
  float* out = (float*)d_out;
  unsigned short* Wh = (unsigned short*)d_ws;                 // 2 MB
  prep_w_kernel<<<dim3((C_OUT*C_IN)/256), dim3(256), 0, stream>>>(W, Wh);
  gemm_kernel<<<dim3(4*8*NBATCH), dim3(256), 0, stream>>>(fea, Wh, b, out);
}

// Round 4
// 291.815 us; speedup vs baseline: 1.1319x; 1.0514x over previous
//
#include <hip/hip_runtime.h>

#define C_IN   2048
#define HWSZ   1024
#define NBATCH 16
#define C_OUT  512
#define BK     64
#define NKSTEP (C_IN/BK)          // 32

typedef __attribute__((ext_vector_type(4))) float f32x4;
typedef __attribute__((ext_vector_type(8))) short bf16x8;

__device__ __forceinline__ unsigned short f2bf(float x){
  unsigned int u = __float_as_uint(x);
  u += 0x7fffu + ((u >> 16) & 1u);          // RNE
  return (unsigned short)(u >> 16);
}

union FU { bf16x8 v; uint4 q; };

// W center tap -> FRAG-MAJOR bf16 in d_ws: the GEMM reads A-fragments as
// single coalesced 1KB global loads (L2-resident, 2MB total), so A never
// touches LDS. Layout: flat = ((((mt*2+wr)*32 + ks)*8 + mf*2+s)*64 + l),
// 8 bf16 each, where o = mt*128+wr*64+mf*16+(l&15),
// c = ks*64 + s*32 + (l>>4)*8 + j   (mfma_16x16x32 A-operand layout).
__global__ void prep_w_kernel(const float* __restrict__ W,
                              unsigned short* __restrict__ Wf){
  const int tid  = blockIdx.x*256 + threadIdx.x;   // 0..131071
  const int l    = tid & 63;
  const int frag = tid >> 6;                       // 0..2047
  const int mfs  = frag & 7;                       // mf*2+s
  const int ks   = (frag >> 3) & 31;
  const int wr   = (frag >> 8) & 1;
  const int mt   = frag >> 9;
  const int o    = mt*128 + wr*64 + (mfs>>1)*16 + (l & 15);
  const int c0   = ks*BK + (mfs & 1)*32 + (l>>4)*8;
  unsigned short v[8];
  #pragma unroll
  for (int j=0;j<8;j++)
    v[j] = f2bf(W[((size_t)o*C_IN + (size_t)(c0 + j))*9 + 4]);
  uint4 pk;
  pk.x = (unsigned)v[0] | ((unsigned)v[1] << 16);
  pk.y = (unsigned)v[2] | ((unsigned)v[3] << 16);
  pk.z = (unsigned)v[4] | ((unsigned)v[5] << 16);
  pk.w = (unsigned)v[6] | ((unsigned)v[7] << 16);
  *(uint4*)(Wf + (size_t)tid*8) = pk;
}

// 2-wave block, tile M128 x N64, wave tile 64x64 (4x4 frags), BK=64.
// B (fea) double-buffered in LDS (2 x 8KB), ONE barrier per K-step.
// A-frags stream from L2 (frag-major Wf). B LDS: [p][k] bf16, 16B chunks
// q=k>>3 swizzled q^(p&7); frag reads 2-way (free), stage writes ~8-way
// (small: 8KB/step).
__global__ __launch_bounds__(128, 2) void gemm_kernel(
    const float* __restrict__ fea,
    const unsigned short* __restrict__ Wf,
    const float* __restrict__ bias,
    float* __restrict__ out)
{
  __shared__ unsigned short Bs[2][64*64];   // 16 KB

  const int t   = threadIdx.x;
  const int l   = t & 63;
  const int wid = t >> 6;                   // wave = M-half

  // XCD-aware decode: 1024 blocks; the 4 mt-blocks sharing a fea panel land
  // on the same XCD (bx step 8 keeps xcd fixed).
  const int bx  = blockIdx.x;
  const int xcd = bx & 7;
  const int s7  = bx >> 3;                  // 0..127
  const int mt  = s7 & 3;
  const int pnl = xcd*32 + (s7 >> 2);       // 0..255
  const int pt  = pnl & 15;                 // p-tile (64 wide)
  const int nb  = pnl >> 4;

  const float* fg = fea + (size_t)nb*C_IN*HWSZ + (size_t)pt*64;
  const unsigned short* wfg = Wf + (size_t)(mt*2 + wid)*131072; // 32*8*64*8

  const int pb = t & 15;                    // p-quad for staging
  const int cb = t >> 4;                    // k-octet for staging (0..7)
  const int fr = l & 15;
  const int o2 = l >> 4;

  f32x4 acc[4][4];
  #pragma unroll
  for (int i=0;i<4;i++)
    #pragma unroll
    for (int j=0;j<4;j++) acc[i][j] = (f32x4)0.0f;

  f32x4 fv[8];
  // prologue: fea tile 0
  #pragma unroll
  for (int i=0;i<8;i++)
    fv[i] = *(const f32x4*)(fg + (size_t)(cb*8 + i)*HWSZ + pb*4);

  for (int ks = 0; ks < NKSTEP; ks++){
    const int cur = ks & 1;
    // ---- cvt + stage B tile ks into buf[cur] (4 x ds_write_b128)
    {
      unsigned short hb[8][4];
      #pragma unroll
      for (int i=0;i<8;i++)
        #pragma unroll
        for (int j=0;j<4;j++) hb[i][j] = f2bf(fv[i][j]);
      #pragma unroll
      for (int j=0;j<4;j++){
        const int p = pb*4 + j;
        uint4 pk;
        pk.x = (unsigned)hb[0][j] | ((unsigned)hb[1][j] << 16);
        pk.y = (unsigned)hb[2][j] | ((unsigned)hb[3][j] << 16);
        pk.z = (unsigned)hb[4][j] | ((unsigned)hb[5][j] << 16);
        pk.w = (unsigned)hb[6][j] | ((unsigned)hb[7][j] << 16);
        *(uint4*)&Bs[cur][p*64 + ((cb ^ (p & 7)) << 3)] = pk;
      }
    }
    __syncthreads();                        // buf[cur] ready; only barrier

    // ---- A-frags for ks: 8 coalesced 1KB loads from L2
    FU af[4][2];
    #pragma unroll
    for (int mf=0; mf<4; mf++)
      #pragma unroll
      for (int s=0; s<2; s++)
        af[mf][s].q = *(const uint4*)(wfg + (size_t)((ks*8 + mf*2 + s)*64 + l)*8);

    // ---- B-frags from LDS (8 x ds_read_b128, 2-way = free)
    FU bf[4][2];
    #pragma unroll
    for (int nf=0; nf<4; nf++){
      const int p = nf*16 + fr;
      #pragma unroll
      for (int s=0; s<2; s++)
        bf[nf][s].q = *(const uint4*)&Bs[cur][p*64 + (((s*4 + o2) ^ (p & 7)) << 3)];
    }

    // ---- fea prefetch ks+1 (in flight across the MFMA block)
    if (ks + 1 < NKSTEP){
      const int c0 = (ks + 1)*BK;
      #pragma unroll
      for (int i=0;i<8;i++)
        fv[i] = *(const f32x4*)(fg + (size_t)(c0 + cb*8 + i)*HWSZ + pb*4);
    }

    // ---- 32 MFMA
    #pragma unroll
    for (int mf=0; mf<4; mf++)
      #pragma unroll
      for (int nf=0; nf<4; nf++){
        acc[mf][nf] = __builtin_amdgcn_mfma_f32_16x16x32_bf16(af[mf][0].v, bf[nf][0].v, acc[mf][nf], 0, 0, 0);
        acc[mf][nf] = __builtin_amdgcn_mfma_f32_16x16x32_bf16(af[mf][1].v, bf[nf][1].v, acc[mf][nf], 0, 0, 0);
      }
  }

  // ---- epilogue: bias + relu + store. C/D: col=lane&15, row=(lane>>4)*4+reg
  float bv[4][4];
  #pragma unroll
  for (int mf=0; mf<4; mf++)
    #pragma unroll
    for (int rr=0; rr<4; rr++)
      bv[mf][rr] = bias[mt*128 + wid*64 + mf*16 + o2*4 + rr];

  float* ob = out + ((size_t)nb*C_OUT + mt*128)*HWSZ + (size_t)pt*64;
  #pragma unroll
  for (int mf=0; mf<4; mf++){
    #pragma unroll
    for (int nf=0; nf<4; nf++){
      const int p = nf*16 + fr;
      #pragma unroll
      for (int rr=0; rr<4; rr++){
        const int o = wid*64 + mf*16 + o2*4 + rr;
        float x = acc[mf][nf][rr] + bv[mf][rr];
        ob[(size_t)o*HWSZ + p] = fmaxf(x, 0.0f);
      }
    }
  }
}

extern "C" void kernel_launch(void* const* d_in, const int* in_sizes, int n_in,
                              void* d_out, int out_size, void* d_ws, size_t ws_size,
                              hipStream_t stream){
  const float* fea = (const float*)d_in[0];
  const float* W   = (const float*)d_in[1];
  const float* b   = (const float*)d_in[2];
  float* out = (float*)d_out;
  unsigned short* Wf = (unsigned short*)d_ws;   // 2 MB frag-major W
  prep_w_kernel<<<dim3(512), dim3(256), 0, stream>>>(W, Wf);
  gemm_kernel<<<dim3(1024), dim3(128), 0, stream>>>(fea, Wf, b, out);
}